// Round 1
// baseline (476.016 us; speedup 1.0000x reference)
//
#include <hip/hip_runtime.h>
#include <hip/hip_bf16.h>

#define SEQ 512
#define NE  192
#define DI  384
#define DS  384
#define DTR 12
#define NPROJ 780   // DTR + 2*DS

__device__ __forceinline__ float fast_sigmoid(float x) {
    return 1.0f / (1.0f + __expf(-x));
}

// ---------------------------------------------------------------------------
// Tiled fp32 GEMM computing  OUT = A (MxK) @ B^T (NxK)  [+ bias]
// BM=BN=64, BK=32, 256 threads, 4x4 micro-tile per thread.
// MODE 0: split into xi (n<384) and silu(res) (n>=384)
// MODE 1: split into dtp (n<12), Bmat (12<=n<396), Cmat (396<=n<780)
// MODE 2: plain store to O0 (out projection)
// ---------------------------------------------------------------------------
template<int MODE>
__launch_bounds__(256)
__global__ void gemm_nt(const float* __restrict__ A, const float* __restrict__ B,
                        const float* __restrict__ bias,
                        float* __restrict__ O0, float* __restrict__ O1, float* __restrict__ O2,
                        int M, int N, int K) {
    __shared__ float As[64][33];
    __shared__ float Bs[64][33];
    const int tid = threadIdx.x;
    const int m0 = blockIdx.y * 64;
    const int n0 = blockIdx.x * 64;
    const int tx = tid & 15;        // -> n
    const int ty = tid >> 4;        // -> m
    const int r  = tid >> 5;        // stage row group 0..7
    const int c  = tid & 31;        // stage k

    float acc[4][4];
    #pragma unroll
    for (int i = 0; i < 4; ++i)
        #pragma unroll
        for (int j = 0; j < 4; ++j) acc[i][j] = 0.0f;

    for (int k0 = 0; k0 < K; k0 += 32) {
        #pragma unroll
        for (int i = 0; i < 8; ++i) {
            const int mr = r + i * 8;
            As[mr][c] = A[(size_t)(m0 + mr) * K + k0 + c];
            const int nr = n0 + r + i * 8;
            Bs[r + i * 8][c] = (nr < N) ? B[(size_t)nr * K + k0 + c] : 0.0f;
        }
        __syncthreads();
        #pragma unroll
        for (int k = 0; k < 32; ++k) {
            float av[4], bv[4];
            #pragma unroll
            for (int i = 0; i < 4; ++i) av[i] = As[ty * 4 + i][k];
            #pragma unroll
            for (int j = 0; j < 4; ++j) bv[j] = Bs[tx * 4 + j][k];
            #pragma unroll
            for (int i = 0; i < 4; ++i)
                #pragma unroll
                for (int j = 0; j < 4; ++j)
                    acc[i][j] = fmaf(av[i], bv[j], acc[i][j]);
        }
        __syncthreads();
    }

    #pragma unroll
    for (int i = 0; i < 4; ++i) {
        const int gm = m0 + ty * 4 + i;
        #pragma unroll
        for (int j = 0; j < 4; ++j) {
            const int gn = n0 + tx * 4 + j;
            if (gn >= N) continue;
            float v = acc[i][j] + (bias ? bias[gn] : 0.0f);
            if (MODE == 0) {
                if (gn < DI) O0[(size_t)gm * DI + gn] = v;
                else         O1[(size_t)gm * DI + (gn - DI)] = v * fast_sigmoid(v); // silu(res)
            } else if (MODE == 1) {
                if (gn < DTR)            O0[(size_t)gm * DTR + gn] = v;
                else if (gn < DTR + DS)  O1[(size_t)gm * DS + (gn - DTR)] = v;
                else                     O2[(size_t)gm * DS + (gn - DTR - DS)] = v;
            } else {
                O0[(size_t)gm * NE + gn] = v;
            }
        }
    }
}

// ---------------------------------------------------------------------------
// Depthwise causal conv (width 4) + SiLU:  u[l,d] = silu(sum_k xi[l-3+k,d]*w[d,k] + b[d])
// ---------------------------------------------------------------------------
__global__ void conv_silu_kernel(const float* __restrict__ xi,
                                 const float* __restrict__ conv_w,
                                 const float* __restrict__ conv_b,
                                 float* __restrict__ u) {
    const int idx = blockIdx.x * blockDim.x + threadIdx.x;
    if (idx >= SEQ * DI) return;
    const int l = idx / DI;
    const int d = idx - l * DI;
    const float4 w = ((const float4*)conv_w)[d];
    float acc = conv_b[d];
    if (l >= 3) acc = fmaf(xi[(size_t)(l - 3) * DI + d], w.x, acc);
    if (l >= 2) acc = fmaf(xi[(size_t)(l - 2) * DI + d], w.y, acc);
    if (l >= 1) acc = fmaf(xi[(size_t)(l - 1) * DI + d], w.z, acc);
    acc = fmaf(xi[(size_t)l * DI + d], w.w, acc);
    u[idx] = acc * fast_sigmoid(acc);
}

// ---------------------------------------------------------------------------
// delta[l,d] = softplus( sum_r dtp[l,r] * W_dt[d,r] ),  K=12
// one block per l (384 threads = one d each)
// ---------------------------------------------------------------------------
__launch_bounds__(DI)
__global__ void delta_kernel(const float* __restrict__ dtp,
                             const float* __restrict__ W_dt,
                             float* __restrict__ delta) {
    const int l = blockIdx.x;
    const int d = threadIdx.x;
    float acc = 0.0f;
    #pragma unroll
    for (int r = 0; r < DTR; ++r)
        acc = fmaf(dtp[l * DTR + r], W_dt[d * DTR + r], acc);
    // softplus, stable
    float sp = (acc > 20.0f) ? acc : log1pf(__expf(acc));
    delta[(size_t)l * DI + d] = sp;
}

// ---------------------------------------------------------------------------
// Selective scan. One block per d (384 blocks x 384 threads, 6 waves).
// Lane owns state n = tid. Waves run independent l-loops (no in-loop barrier);
// per-l 64-lane butterfly -> LDS partial; single merge at the end which also
// fuses  yfin = (y + u*D) * silu(res).
// ---------------------------------------------------------------------------
__launch_bounds__(DI)
__global__ void scan_kernel(const float* __restrict__ delta,
                            const float* __restrict__ u,
                            const float* __restrict__ Bmat,
                            const float* __restrict__ Cmat,
                            const float* __restrict__ A_log,
                            const float* __restrict__ Dvec,
                            const float* __restrict__ sres,
                            float* __restrict__ yfin) {
    const int d   = blockIdx.x;
    const int tid = threadIdx.x;
    const int n   = tid;
    const int w   = tid >> 6;

    __shared__ float part[6][SEQ];   // 12 KB

    const float a = -__expf(A_log[(size_t)d * DS + n]);
    float h = 0.0f;

    const float* __restrict__ dp = delta + d;   // uniform per block -> s_load
    const float* __restrict__ up = u + d;
    const float* __restrict__ bp = Bmat + n;
    const float* __restrict__ cp = Cmat + n;

    #pragma unroll 4
    for (int l = 0; l < SEQ; ++l) {
        const float dt = dp[(size_t)l * DI];
        const float uu = up[(size_t)l * DI];
        const float b  = bp[(size_t)l * DS];
        const float c  = cp[(size_t)l * DS];
        const float dA = __expf(dt * a);
        h = fmaf(dA, h, (dt * uu) * b);
        float p = h * c;
        p += __shfl_xor(p, 1);
        p += __shfl_xor(p, 2);
        p += __shfl_xor(p, 4);
        p += __shfl_xor(p, 8);
        p += __shfl_xor(p, 16);
        p += __shfl_xor(p, 32);
        if ((tid & 63) == 0) part[w][l] = p;
    }
    __syncthreads();

    const float Dd = Dvec[d];
    for (int l = tid; l < SEQ; l += DI) {
        const float y = part[0][l] + part[1][l] + part[2][l]
                      + part[3][l] + part[4][l] + part[5][l];
        const float uv = u[(size_t)l * DI + d];
        const float sr = sres[(size_t)l * DI + d];
        yfin[(size_t)l * DI + d] = (y + uv * Dd) * sr;
    }
}

// ---------------------------------------------------------------------------
extern "C" void kernel_launch(void* const* d_in, const int* in_sizes, int n_in,
                              void* d_out, int out_size, void* d_ws, size_t ws_size,
                              hipStream_t stream) {
    const float* x      = (const float*)d_in[0];
    const float* W_in   = (const float*)d_in[1];
    const float* b_in   = (const float*)d_in[2];
    const float* conv_w = (const float*)d_in[3];
    const float* conv_b = (const float*)d_in[4];
    const float* W_xp   = (const float*)d_in[5];
    const float* W_dt   = (const float*)d_in[6];
    const float* A_log  = (const float*)d_in[7];
    const float* Dvec   = (const float*)d_in[8];
    const float* W_out  = (const float*)d_in[9];
    const float* b_out  = (const float*)d_in[10];
    float* out = (float*)d_out;

    float* ws = (float*)d_ws;
    const size_t LD = (size_t)SEQ * DI;   // 196608
    float* xi    = ws;
    float* sres  = ws + LD;
    float* u     = ws + 2 * LD;
    float* Bm    = ws + 3 * LD;
    float* Cm    = ws + 4 * LD;
    float* delta = ws + 5 * LD;
    float* dtp   = ws + 6 * LD;               // 512*12
    float* yfin  = ws + 6 * LD + SEQ * DTR;

    // 1) in-projection: xr = x @ W_in^T + b_in -> xi | silu(res)
    gemm_nt<0><<<dim3(12, 8), 256, 0, stream>>>(x, W_in, b_in, xi, sres, nullptr,
                                                SEQ, 2 * DI, NE);
    // 2) depthwise conv + silu -> u
    conv_silu_kernel<<<(SEQ * DI + 255) / 256, 256, 0, stream>>>(xi, conv_w, conv_b, u);
    // 3) x-projection: dbc = u @ W_xp^T -> dtp | B | C
    gemm_nt<1><<<dim3(13, 8), 256, 0, stream>>>(u, W_xp, nullptr, dtp, Bm, Cm,
                                                SEQ, NPROJ, DI);
    // 4) delta = softplus(dtp @ W_dt^T)
    delta_kernel<<<SEQ, DI, 0, stream>>>(dtp, W_dt, delta);
    // 5) selective scan + gating fused -> yfin
    scan_kernel<<<DI, DI, 0, stream>>>(delta, u, Bm, Cm, A_log, Dvec, sres, yfin);
    // 6) out projection: out = yfin @ W_out^T + b_out
    gemm_nt<2><<<dim3(3, 8), 256, 0, stream>>>(yfin, W_out, b_out, out, nullptr, nullptr,
                                               SEQ, NE, DI);
}

// Round 2
// 327.934 us; speedup vs baseline: 1.4516x; 1.4516x over previous
//
#include <hip/hip_runtime.h>
#include <hip/hip_bf16.h>

#define SEQ 512
#define NE  192
#define DI  384
#define DS  384
#define DTR 12
#define NPROJ 780   // DTR + 2*DS
#define NC  8       // chunks
#define LC  64      // SEQ / NC

__device__ __forceinline__ float fast_sigmoid(float x) {
    return 1.0f / (1.0f + __expf(-x));
}

// DPP-based wave64 reduction step: x + dpp_shifted(x). Sum lands in lane 63.
template<int CTRL>
__device__ __forceinline__ float dpp_add(float x) {
    int v = __builtin_amdgcn_update_dpp(0, __float_as_int(x), CTRL, 0xf, 0xf, false);
    return x + __int_as_float(v);
}
__device__ __forceinline__ float wave_reduce63(float p) {
    p = dpp_add<0x111>(p);  // row_shr:1
    p = dpp_add<0x112>(p);  // row_shr:2
    p = dpp_add<0x114>(p);  // row_shr:4
    p = dpp_add<0x118>(p);  // row_shr:8  -> lane 15/31/47/63 hold row sums
    p = dpp_add<0x142>(p);  // row_bcast:15
    p = dpp_add<0x143>(p);  // row_bcast:31 -> lane 63 holds full sum
    return p;
}

// ---------------------------------------------------------------------------
// Tiled fp32 GEMM computing  OUT = A (MxK) @ B^T (NxK)  [+ bias]
// ---------------------------------------------------------------------------
template<int MODE>
__launch_bounds__(256)
__global__ void gemm_nt(const float* __restrict__ A, const float* __restrict__ B,
                        const float* __restrict__ bias,
                        float* __restrict__ O0, float* __restrict__ O1, float* __restrict__ O2,
                        int M, int N, int K) {
    __shared__ float As[64][33];
    __shared__ float Bs[64][33];
    const int tid = threadIdx.x;
    const int m0 = blockIdx.y * 64;
    const int n0 = blockIdx.x * 64;
    const int tx = tid & 15;
    const int ty = tid >> 4;
    const int r  = tid >> 5;
    const int c  = tid & 31;

    float acc[4][4];
    #pragma unroll
    for (int i = 0; i < 4; ++i)
        #pragma unroll
        for (int j = 0; j < 4; ++j) acc[i][j] = 0.0f;

    for (int k0 = 0; k0 < K; k0 += 32) {
        #pragma unroll
        for (int i = 0; i < 8; ++i) {
            const int mr = r + i * 8;
            As[mr][c] = A[(size_t)(m0 + mr) * K + k0 + c];
            const int nr = n0 + r + i * 8;
            Bs[r + i * 8][c] = (nr < N) ? B[(size_t)nr * K + k0 + c] : 0.0f;
        }
        __syncthreads();
        #pragma unroll
        for (int k = 0; k < 32; ++k) {
            float av[4], bv[4];
            #pragma unroll
            for (int i = 0; i < 4; ++i) av[i] = As[ty * 4 + i][k];
            #pragma unroll
            for (int j = 0; j < 4; ++j) bv[j] = Bs[tx * 4 + j][k];
            #pragma unroll
            for (int i = 0; i < 4; ++i)
                #pragma unroll
                for (int j = 0; j < 4; ++j)
                    acc[i][j] = fmaf(av[i], bv[j], acc[i][j]);
        }
        __syncthreads();
    }

    #pragma unroll
    for (int i = 0; i < 4; ++i) {
        const int gm = m0 + ty * 4 + i;
        #pragma unroll
        for (int j = 0; j < 4; ++j) {
            const int gn = n0 + tx * 4 + j;
            if (gn >= N) continue;
            float v = acc[i][j] + (bias ? bias[gn] : 0.0f);
            if (MODE == 0) {
                if (gn < DI) O0[(size_t)gm * DI + gn] = v;
                else         O1[(size_t)gm * DI + (gn - DI)] = v * fast_sigmoid(v);
            } else if (MODE == 1) {
                if (gn < DTR)            O0[(size_t)gm * DTR + gn] = v;
                else if (gn < DTR + DS)  O1[(size_t)gm * DS + (gn - DTR)] = v;
                else                     O2[(size_t)gm * DS + (gn - DTR - DS)] = v;
            } else {
                O0[(size_t)gm * NE + gn] = v;
            }
        }
    }
}

// ---------------------------------------------------------------------------
__global__ void conv_silu_kernel(const float* __restrict__ xi,
                                 const float* __restrict__ conv_w,
                                 const float* __restrict__ conv_b,
                                 float* __restrict__ u) {
    const int idx = blockIdx.x * blockDim.x + threadIdx.x;
    if (idx >= SEQ * DI) return;
    const int l = idx / DI;
    const int d = idx - l * DI;
    const float4 w = ((const float4*)conv_w)[d];
    float acc = conv_b[d];
    if (l >= 3) acc = fmaf(xi[(size_t)(l - 3) * DI + d], w.x, acc);
    if (l >= 2) acc = fmaf(xi[(size_t)(l - 2) * DI + d], w.y, acc);
    if (l >= 1) acc = fmaf(xi[(size_t)(l - 1) * DI + d], w.z, acc);
    acc = fmaf(xi[(size_t)l * DI + d], w.w, acc);
    u[idx] = acc * fast_sigmoid(acc);
}

// ---------------------------------------------------------------------------
__launch_bounds__(DI)
__global__ void delta_kernel(const float* __restrict__ dtp,
                             const float* __restrict__ W_dt,
                             float* __restrict__ delta) {
    const int l = blockIdx.x;
    const int d = threadIdx.x;
    float acc = 0.0f;
    #pragma unroll
    for (int r = 0; r < DTR; ++r)
        acc = fmaf(dtp[l * DTR + r], W_dt[d * DTR + r], acc);
    float sp = (acc > 20.0f) ? acc : log1pf(__expf(acc));
    delta[(size_t)l * DI + d] = sp;
}

// ---------------------------------------------------------------------------
// Phase A: chunk-local scan. Block = (chunk k, channel d), 384 threads (n=tid).
// Computes ylocal[d, l] (scan with h_start = 0), hend[d,k,n] (local final
// state) and Schunk[d,k] = sum of dt over the chunk.
// ---------------------------------------------------------------------------
__launch_bounds__(DI)
__global__ void scanA_kernel(const float* __restrict__ delta,
                             const float* __restrict__ u,
                             const float* __restrict__ Bmat,
                             const float* __restrict__ Cmat,
                             const float* __restrict__ A_log,
                             float* __restrict__ ylocal,
                             float* __restrict__ hend,
                             float* __restrict__ Schunk) {
    const int k   = blockIdx.x;
    const int d   = blockIdx.y;
    const int tid = threadIdx.x;
    const int n   = tid;
    const int w   = tid >> 6;
    const int l0  = k * LC;

    __shared__ float s_dt[LC];
    __shared__ float s_u[LC];
    __shared__ float part[6][LC];

    if (tid < LC)            s_dt[tid]      = delta[(size_t)(l0 + tid) * DI + d];
    else if (tid < 2 * LC)   s_u[tid - LC]  = u[(size_t)(l0 + tid - LC) * DI + d];
    __syncthreads();

    const float a = -__expf(A_log[(size_t)d * DS + n]);
    float h = 0.0f;
    float S = 0.0f;

    const float* __restrict__ bp = Bmat + (size_t)l0 * DS + n;
    const float* __restrict__ cp = Cmat + (size_t)l0 * DS + n;

    #pragma unroll 4
    for (int l = 0; l < LC; ++l) {
        const float dt = s_dt[l];
        const float uu = s_u[l];
        const float b  = bp[(size_t)l * DS];
        const float c  = cp[(size_t)l * DS];
        S += dt;
        const float dA = __expf(dt * a);
        h = fmaf(dA, h, (dt * uu) * b);
        float p = wave_reduce63(h * c);
        if ((tid & 63) == 63) part[w][l] = p;
    }

    hend[(size_t)(d * NC + k) * DS + n] = h;
    if (tid == 0) Schunk[d * NC + k] = S;
    __syncthreads();

    if (tid < LC) {
        const int l = tid;
        ylocal[(size_t)d * SEQ + l0 + l] =
            part[0][l] + part[1][l] + part[2][l] + part[3][l] + part[4][l] + part[5][l];
    }
}

// ---------------------------------------------------------------------------
// Phase B: cross-chunk state combine. Block = d, lane = n.
// Rewrites hend[d,k,:] in place to hold h_start for chunk k (state BEFORE it).
// ---------------------------------------------------------------------------
__launch_bounds__(DI)
__global__ void scanB_kernel(const float* __restrict__ A_log,
                             const float* __restrict__ Schunk,
                             float* __restrict__ hend) {
    const int d = blockIdx.x;
    const int n = threadIdx.x;
    const float a = -__expf(A_log[(size_t)d * DS + n]);
    float H = 0.0f;   // state entering chunk 0
    #pragma unroll
    for (int k = 0; k < NC; ++k) {
        const float prev = H;
        const float dtot = __expf(a * Schunk[d * NC + k]);
        const float he   = hend[(size_t)(d * NC + k) * DS + n];
        H = fmaf(dtot, H, he);
        hend[(size_t)(d * NC + k) * DS + n] = prev;  // h_start for chunk k
    }
}

// ---------------------------------------------------------------------------
// Phase C: correction sweep + gating. Block = (chunk k, channel d).
// y[l] = ylocal[l] + C_l . (P_l ⊙ h_start);  yfin = (y + u*D) * silu(res)
// ---------------------------------------------------------------------------
__launch_bounds__(DI)
__global__ void scanC_kernel(const float* __restrict__ delta,
                             const float* __restrict__ u,
                             const float* __restrict__ Cmat,
                             const float* __restrict__ A_log,
                             const float* __restrict__ Dvec,
                             const float* __restrict__ sres,
                             const float* __restrict__ ylocal,
                             const float* __restrict__ hstart,
                             float* __restrict__ yfin) {
    const int k   = blockIdx.x;
    const int d   = blockIdx.y;
    const int tid = threadIdx.x;
    const int n   = tid;
    const int w   = tid >> 6;
    const int l0  = k * LC;

    __shared__ float s_dt[LC];
    __shared__ float part[6][LC];

    if (k > 0) {
        if (tid < LC) s_dt[tid] = delta[(size_t)(l0 + tid) * DI + d];
        __syncthreads();

        const float a = -__expf(A_log[(size_t)d * DS + n]);
        float q = hstart[(size_t)(d * NC + k) * DS + n];
        const float* __restrict__ cp = Cmat + (size_t)l0 * DS + n;

        #pragma unroll 4
        for (int l = 0; l < LC; ++l) {
            const float dt = s_dt[l];
            q *= __expf(dt * a);
            float p = wave_reduce63(q * cp[(size_t)l * DS]);
            if ((tid & 63) == 63) part[w][l] = p;
        }
        __syncthreads();
    }

    if (tid < LC) {
        const int l = l0 + tid;
        float y = ylocal[(size_t)d * SEQ + l];
        if (k > 0)
            y += part[0][tid] + part[1][tid] + part[2][tid]
               + part[3][tid] + part[4][tid] + part[5][tid];
        const float uv = u[(size_t)l * DI + d];
        const float sr = sres[(size_t)l * DI + d];
        yfin[(size_t)l * DI + d] = (y + uv * Dvec[d]) * sr;
    }
}

// ---------------------------------------------------------------------------
extern "C" void kernel_launch(void* const* d_in, const int* in_sizes, int n_in,
                              void* d_out, int out_size, void* d_ws, size_t ws_size,
                              hipStream_t stream) {
    const float* x      = (const float*)d_in[0];
    const float* W_in   = (const float*)d_in[1];
    const float* b_in   = (const float*)d_in[2];
    const float* conv_w = (const float*)d_in[3];
    const float* conv_b = (const float*)d_in[4];
    const float* W_xp   = (const float*)d_in[5];
    const float* W_dt   = (const float*)d_in[6];
    const float* A_log  = (const float*)d_in[7];
    const float* Dvec   = (const float*)d_in[8];
    const float* W_out  = (const float*)d_in[9];
    const float* b_out  = (const float*)d_in[10];
    float* out = (float*)d_out;

    float* ws = (float*)d_ws;
    const size_t LD = (size_t)SEQ * DI;   // 196608
    float* xi     = ws;
    float* sres   = ws + LD;
    float* u      = ws + 2 * LD;
    float* Bm     = ws + 3 * LD;
    float* Cm     = ws + 4 * LD;
    float* delta  = ws + 5 * LD;
    float* dtp    = ws + 6 * LD;                    // SEQ*DTR
    float* yfin   = ws + 6 * LD + SEQ * DTR;
    float* ylocal = ws + 7 * LD + SEQ * DTR;        // [DI][SEQ]
    float* hend   = ws + 8 * LD + SEQ * DTR;        // [DI][NC][DS] (then h_start in place)
    float* Schunk = hend + (size_t)DI * NC * DS;    // [DI][NC]

    gemm_nt<0><<<dim3(12, 8), 256, 0, stream>>>(x, W_in, b_in, xi, sres, nullptr,
                                                SEQ, 2 * DI, NE);
    conv_silu_kernel<<<(SEQ * DI + 255) / 256, 256, 0, stream>>>(xi, conv_w, conv_b, u);
    gemm_nt<1><<<dim3(13, 8), 256, 0, stream>>>(u, W_xp, nullptr, dtp, Bm, Cm,
                                                SEQ, NPROJ, DI);
    delta_kernel<<<SEQ, DI, 0, stream>>>(dtp, W_dt, delta);

    scanA_kernel<<<dim3(NC, DI), DI, 0, stream>>>(delta, u, Bm, Cm, A_log,
                                                  ylocal, hend, Schunk);
    scanB_kernel<<<DI, DI, 0, stream>>>(A_log, Schunk, hend);
    scanC_kernel<<<dim3(NC, DI), DI, 0, stream>>>(delta, u, Cm, A_log, Dvec, sres,
                                                  ylocal, hend, yfin);

    gemm_nt<2><<<dim3(3, 8), 256, 0, stream>>>(yfin, W_out, b_out, out, nullptr, nullptr,
                                               SEQ, NE, DI);
}

// Round 3
// 242.407 us; speedup vs baseline: 1.9637x; 1.3528x over previous
//
#include <hip/hip_runtime.h>
#include <hip/hip_bf16.h>

#define SEQ 512
#define NE  192
#define DI  384
#define DS  384
#define DTR 12
#define NC  8       // chunks
#define LC  64      // SEQ / NC

__device__ __forceinline__ float fast_sigmoid(float x) {
    return 1.0f / (1.0f + __expf(-x));
}

// DPP-based wave64 reduction: sum lands in lane 63.
template<int CTRL>
__device__ __forceinline__ float dpp_add(float x) {
    int v = __builtin_amdgcn_update_dpp(0, __float_as_int(x), CTRL, 0xf, 0xf, false);
    return x + __int_as_float(v);
}
__device__ __forceinline__ float wave_reduce63(float p) {
    p = dpp_add<0x111>(p);  // row_shr:1
    p = dpp_add<0x112>(p);  // row_shr:2
    p = dpp_add<0x114>(p);  // row_shr:4
    p = dpp_add<0x118>(p);  // row_shr:8
    p = dpp_add<0x142>(p);  // row_bcast:15
    p = dpp_add<0x143>(p);  // row_bcast:31
    return p;
}

// ---------------------------------------------------------------------------
// prep: Wd[n][k] = sum_r W_dt[n][r] * W_xp[r][k]   (384x384, K=12)
// block = n (384 blocks), thread = k (384 threads)
// ---------------------------------------------------------------------------
__launch_bounds__(DI)
__global__ void prep_wd(const float* __restrict__ W_dt, const float* __restrict__ W_xp,
                        float* __restrict__ Wd) {
    const int n = blockIdx.x;
    const int k = threadIdx.x;
    float acc = 0.0f;
    #pragma unroll
    for (int r = 0; r < DTR; ++r)
        acc = fmaf(W_dt[n * DTR + r], W_xp[r * DI + k], acc);
    Wd[(size_t)n * DI + k] = acc;
}

// ---------------------------------------------------------------------------
// Tiled fp32 GEMM:  OUT = A (MxK) @ B^T (NxK) [+bias]
// 64x64 tile, BK=32, 256 threads, register-prefetch double buffering,
// transposed LDS (As[k][m]) so fragments are ds_read_b128.
// All of M, N, K are multiples of the tile sizes here (no bounds checks).
// MODE 0: n<384 -> xi ; else -> sres = silu(v)
// MODE 1: n<384 -> delta = softplus(v) ; n<768 -> B ; else -> C
//         (B matrix rows <384 come from Bsrc0=Wd, rows >=384 from Bsrc1=W_xp+12)
// MODE 2: plain + bias (out projection)
// ---------------------------------------------------------------------------
template<int MODE>
__launch_bounds__(256)
__global__ void gemm_nt(const float* __restrict__ A,
                        const float* __restrict__ Bsrc0,
                        const float* __restrict__ Bsrc1,
                        const float* __restrict__ bias,
                        float* __restrict__ O0, float* __restrict__ O1, float* __restrict__ O2,
                        int M, int N, int K) {
    __shared__ float Asm[32][68];
    __shared__ float Bsm[32][68];
    const int tid = threadIdx.x;
    const int m0 = blockIdx.y * 64;
    const int n0 = blockIdx.x * 64;
    const int tx = tid & 15;
    const int ty = tid >> 4;
    const int r  = tid >> 5;        // 0..7
    const int c  = tid & 31;        // k within tile

    float regA[8], regB[8];
    const int NK = K >> 5;

    auto load_regs = [&](int kk) {
        #pragma unroll
        for (int i = 0; i < 8; ++i) {
            const int mr = r + i * 8;
            regA[i] = A[(size_t)(m0 + mr) * K + kk + c];
            const int nr = n0 + r + i * 8;
            const float* brow = (MODE == 1 && nr >= DI)
                              ? (Bsrc1 + (size_t)(nr - DI + DTR) * K)
                              : (Bsrc0 + (size_t)nr * K);
            regB[i] = brow[kk + c];
        }
    };

    float acc[4][4];
    #pragma unroll
    for (int i = 0; i < 4; ++i)
        #pragma unroll
        for (int j = 0; j < 4; ++j) acc[i][j] = 0.0f;

    load_regs(0);
    for (int it = 0; it < NK; ++it) {
        if (it > 0) __syncthreads();
        #pragma unroll
        for (int i = 0; i < 8; ++i) {
            Asm[c][r + i * 8] = regA[i];
            Bsm[c][r + i * 8] = regB[i];
        }
        __syncthreads();
        if (it + 1 < NK) load_regs((it + 1) << 5);
        #pragma unroll
        for (int k = 0; k < 32; ++k) {
            const float4 av = *(const float4*)&Asm[k][ty * 4];
            const float4 bv = *(const float4*)&Bsm[k][tx * 4];
            acc[0][0] = fmaf(av.x, bv.x, acc[0][0]);
            acc[0][1] = fmaf(av.x, bv.y, acc[0][1]);
            acc[0][2] = fmaf(av.x, bv.z, acc[0][2]);
            acc[0][3] = fmaf(av.x, bv.w, acc[0][3]);
            acc[1][0] = fmaf(av.y, bv.x, acc[1][0]);
            acc[1][1] = fmaf(av.y, bv.y, acc[1][1]);
            acc[1][2] = fmaf(av.y, bv.z, acc[1][2]);
            acc[1][3] = fmaf(av.y, bv.w, acc[1][3]);
            acc[2][0] = fmaf(av.z, bv.x, acc[2][0]);
            acc[2][1] = fmaf(av.z, bv.y, acc[2][1]);
            acc[2][2] = fmaf(av.z, bv.z, acc[2][2]);
            acc[2][3] = fmaf(av.z, bv.w, acc[2][3]);
            acc[3][0] = fmaf(av.w, bv.x, acc[3][0]);
            acc[3][1] = fmaf(av.w, bv.y, acc[3][1]);
            acc[3][2] = fmaf(av.w, bv.z, acc[3][2]);
            acc[3][3] = fmaf(av.w, bv.w, acc[3][3]);
        }
    }

    #pragma unroll
    for (int i = 0; i < 4; ++i) {
        const int gm = m0 + ty * 4 + i;
        #pragma unroll
        for (int j = 0; j < 4; ++j) {
            const int gn = n0 + tx * 4 + j;
            float v = acc[i][j] + (bias ? bias[gn] : 0.0f);
            if (MODE == 0) {
                if (gn < DI) O0[(size_t)gm * DI + gn] = v;
                else         O1[(size_t)gm * DI + (gn - DI)] = v * fast_sigmoid(v);
            } else if (MODE == 1) {
                if (gn < DI) {
                    float sp = (v > 20.0f) ? v : log1pf(__expf(v));
                    O0[(size_t)gm * DI + gn] = sp;               // delta
                } else if (gn < 2 * DI) {
                    O1[(size_t)gm * DS + (gn - DI)] = v;         // B
                } else {
                    O2[(size_t)gm * DS + (gn - 2 * DI)] = v;     // C
                }
            } else {
                O0[(size_t)gm * NE + gn] = v;
            }
        }
    }
}

// ---------------------------------------------------------------------------
__global__ void conv_silu_kernel(const float* __restrict__ xi,
                                 const float* __restrict__ conv_w,
                                 const float* __restrict__ conv_b,
                                 float* __restrict__ u) {
    const int idx = blockIdx.x * blockDim.x + threadIdx.x;
    if (idx >= SEQ * DI) return;
    const int l = idx / DI;
    const int d = idx - l * DI;
    const float4 w = ((const float4*)conv_w)[d];
    float acc = conv_b[d];
    if (l >= 3) acc = fmaf(xi[(size_t)(l - 3) * DI + d], w.x, acc);
    if (l >= 2) acc = fmaf(xi[(size_t)(l - 2) * DI + d], w.y, acc);
    if (l >= 1) acc = fmaf(xi[(size_t)(l - 1) * DI + d], w.z, acc);
    acc = fmaf(xi[(size_t)l * DI + d], w.w, acc);
    u[idx] = acc * fast_sigmoid(acc);
}

// ---------------------------------------------------------------------------
// Phase A: chunk-local scan. Block = (chunk k, channel d), 384 threads (n=tid).
// ---------------------------------------------------------------------------
__launch_bounds__(DI)
__global__ void scanA_kernel(const float* __restrict__ delta,
                             const float* __restrict__ u,
                             const float* __restrict__ Bmat,
                             const float* __restrict__ Cmat,
                             const float* __restrict__ A_log,
                             float* __restrict__ ylocal,
                             float* __restrict__ hend,
                             float* __restrict__ Schunk) {
    const int k   = blockIdx.x;
    const int d   = blockIdx.y;
    const int tid = threadIdx.x;
    const int n   = tid;
    const int w   = tid >> 6;
    const int l0  = k * LC;

    __shared__ float s_dt[LC];
    __shared__ float s_u[LC];
    __shared__ float part[6][LC];

    if (tid < LC)            s_dt[tid]      = delta[(size_t)(l0 + tid) * DI + d];
    else if (tid < 2 * LC)   s_u[tid - LC]  = u[(size_t)(l0 + tid - LC) * DI + d];
    __syncthreads();

    const float a = -__expf(A_log[(size_t)d * DS + n]);
    float h = 0.0f;
    float S = 0.0f;

    const float* __restrict__ bp = Bmat + (size_t)l0 * DS + n;
    const float* __restrict__ cp = Cmat + (size_t)l0 * DS + n;

    #pragma unroll 4
    for (int l = 0; l < LC; ++l) {
        const float dt = s_dt[l];
        const float uu = s_u[l];
        const float b  = bp[(size_t)l * DS];
        const float c  = cp[(size_t)l * DS];
        S += dt;
        const float dA = __expf(dt * a);
        h = fmaf(dA, h, (dt * uu) * b);
        float p = wave_reduce63(h * c);
        if ((tid & 63) == 63) part[w][l] = p;
    }

    hend[(size_t)(d * NC + k) * DS + n] = h;
    if (tid == 0) Schunk[d * NC + k] = S;
    __syncthreads();

    if (tid < LC) {
        const int l = tid;
        ylocal[(size_t)d * SEQ + l0 + l] =
            part[0][l] + part[1][l] + part[2][l] + part[3][l] + part[4][l] + part[5][l];
    }
}

// ---------------------------------------------------------------------------
// Phase B: cross-chunk combine; hend[d,k,:] becomes h_start for chunk k.
// ---------------------------------------------------------------------------
__launch_bounds__(DI)
__global__ void scanB_kernel(const float* __restrict__ A_log,
                             const float* __restrict__ Schunk,
                             float* __restrict__ hend) {
    const int d = blockIdx.x;
    const int n = threadIdx.x;
    const float a = -__expf(A_log[(size_t)d * DS + n]);
    float H = 0.0f;
    #pragma unroll
    for (int k = 0; k < NC; ++k) {
        const float prev = H;
        const float dtot = __expf(a * Schunk[d * NC + k]);
        const float he   = hend[(size_t)(d * NC + k) * DS + n];
        H = fmaf(dtot, H, he);
        hend[(size_t)(d * NC + k) * DS + n] = prev;
    }
}

// ---------------------------------------------------------------------------
// Phase C: correction + gating.
// ---------------------------------------------------------------------------
__launch_bounds__(DI)
__global__ void scanC_kernel(const float* __restrict__ delta,
                             const float* __restrict__ u,
                             const float* __restrict__ Cmat,
                             const float* __restrict__ A_log,
                             const float* __restrict__ Dvec,
                             const float* __restrict__ sres,
                             const float* __restrict__ ylocal,
                             const float* __restrict__ hstart,
                             float* __restrict__ yfin) {
    const int k   = blockIdx.x;
    const int d   = blockIdx.y;
    const int tid = threadIdx.x;
    const int n   = tid;
    const int w   = tid >> 6;
    const int l0  = k * LC;

    __shared__ float s_dt[LC];
    __shared__ float part[6][LC];

    if (k > 0) {
        if (tid < LC) s_dt[tid] = delta[(size_t)(l0 + tid) * DI + d];
        __syncthreads();

        const float a = -__expf(A_log[(size_t)d * DS + n]);
        float q = hstart[(size_t)(d * NC + k) * DS + n];
        const float* __restrict__ cp = Cmat + (size_t)l0 * DS + n;

        #pragma unroll 4
        for (int l = 0; l < LC; ++l) {
            const float dt = s_dt[l];
            q *= __expf(dt * a);
            float p = wave_reduce63(q * cp[(size_t)l * DS]);
            if ((tid & 63) == 63) part[w][l] = p;
        }
        __syncthreads();
    }

    if (tid < LC) {
        const int l = l0 + tid;
        float y = ylocal[(size_t)d * SEQ + l];
        if (k > 0)
            y += part[0][tid] + part[1][tid] + part[2][tid]
               + part[3][tid] + part[4][tid] + part[5][tid];
        const float uv = u[(size_t)l * DI + d];
        const float sr = sres[(size_t)l * DI + d];
        yfin[(size_t)l * DI + d] = (y + uv * Dvec[d]) * sr;
    }
}

// ---------------------------------------------------------------------------
extern "C" void kernel_launch(void* const* d_in, const int* in_sizes, int n_in,
                              void* d_out, int out_size, void* d_ws, size_t ws_size,
                              hipStream_t stream) {
    const float* x      = (const float*)d_in[0];
    const float* W_in   = (const float*)d_in[1];
    const float* b_in   = (const float*)d_in[2];
    const float* conv_w = (const float*)d_in[3];
    const float* conv_b = (const float*)d_in[4];
    const float* W_xp   = (const float*)d_in[5];
    const float* W_dt   = (const float*)d_in[6];
    const float* A_log  = (const float*)d_in[7];
    const float* Dvec   = (const float*)d_in[8];
    const float* W_out  = (const float*)d_in[9];
    const float* b_out  = (const float*)d_in[10];
    float* out = (float*)d_out;

    float* ws = (float*)d_ws;
    const size_t LD = (size_t)SEQ * DI;   // 196608
    float* xi     = ws;
    float* sres   = ws + LD;
    float* u      = ws + 2 * LD;
    float* Bm     = ws + 3 * LD;
    float* Cm     = ws + 4 * LD;
    float* delta  = ws + 5 * LD;
    float* yfin   = ws + 6 * LD;
    float* ylocal = ws + 7 * LD;                    // [DI][SEQ]
    float* hend   = ws + 8 * LD;                    // [DI][NC][DS]
    float* Schunk = hend + (size_t)DI * NC * DS;    // [DI][NC]
    float* Wd     = Schunk + (size_t)DI * NC;       // [DI][DI]

    // 0) Wd = W_dt @ W_xp[:12]   (fuses delta projection into the big gemm)
    prep_wd<<<DI, DI, 0, stream>>>(W_dt, W_xp, Wd);
    // 1) in-projection -> xi | sres
    gemm_nt<0><<<dim3(12, 8), 256, 0, stream>>>(x, W_in, nullptr, b_in,
                                                xi, sres, nullptr, SEQ, 2 * DI, NE);
    // 2) conv + silu -> u
    conv_silu_kernel<<<(SEQ * DI + 255) / 256, 256, 0, stream>>>(xi, conv_w, conv_b, u);
    // 3) big projection -> delta | B | C   (N = 1152)
    gemm_nt<1><<<dim3(18, 8), 256, 0, stream>>>(u, Wd, W_xp, nullptr,
                                                delta, Bm, Cm, SEQ, 3 * DI, DI);
    // 4) chunked scan
    scanA_kernel<<<dim3(NC, DI), DI, 0, stream>>>(delta, u, Bm, Cm, A_log,
                                                  ylocal, hend, Schunk);
    scanB_kernel<<<DI, DI, 0, stream>>>(A_log, Schunk, hend);
    scanC_kernel<<<dim3(NC, DI), DI, 0, stream>>>(delta, u, Cm, A_log, Dvec, sres,
                                                  ylocal, hend, yfin);
    // 5) out projection
    gemm_nt<2><<<dim3(3, 8), 256, 0, stream>>>(yfin, W_out, nullptr, b_out,
                                               out, nullptr, nullptr, SEQ, NE, DI);
}

// Round 4
// 214.036 us; speedup vs baseline: 2.2240x; 1.1325x over previous
//
#include <hip/hip_runtime.h>
#include <hip/hip_bf16.h>

#define SEQ 512
#define NE  192
#define DI  384
#define DS  384
#define DTR 12
#define NC  8       // chunks
#define LC  64      // SEQ / NC

#if __has_builtin(__builtin_amdgcn_exp2f)
#define EXP2F(x) __builtin_amdgcn_exp2f(x)
#else
#define EXP2F(x) __expf((x) * 0.69314718056f)
#endif
#define LOG2E 1.44269504089f

__device__ __forceinline__ float fast_sigmoid(float x) {
    return 1.0f / (1.0f + __expf(-x));
}

// DPP add: x + shifted(x); invalid lanes contribute 0.
template<int CTRL>
__device__ __forceinline__ float dpp_add(float x) {
    int v = __builtin_amdgcn_update_dpp(0, __float_as_int(x), CTRL, 0xf, 0xf, false);
    return x + __int_as_float(v);
}
// 4-step row reduction: lanes 15/31/47/63 hold their 16-lane row sums.
__device__ __forceinline__ float row_reduce16(float p) {
    p = dpp_add<0x111>(p);  // row_shr:1
    p = dpp_add<0x112>(p);  // row_shr:2
    p = dpp_add<0x114>(p);  // row_shr:4
    p = dpp_add<0x118>(p);  // row_shr:8
    return p;
}

// ---------------------------------------------------------------------------
// prep: Wd[n][k] = sum_r W_dt[n][r] * W_xp[r][k]   (384x384, K=12)
// ---------------------------------------------------------------------------
__launch_bounds__(DI)
__global__ void prep_wd(const float* __restrict__ W_dt, const float* __restrict__ W_xp,
                        float* __restrict__ Wd) {
    const int n = blockIdx.x;
    const int k = threadIdx.x;
    float acc = 0.0f;
    #pragma unroll
    for (int r = 0; r < DTR; ++r)
        acc = fmaf(W_dt[n * DTR + r], W_xp[r * DI + k], acc);
    Wd[(size_t)n * DI + k] = acc;
}

// ---------------------------------------------------------------------------
// Tiled fp32 GEMM:  OUT = A (MxK) @ B^T (NxK) [+bias]
// 64x64 tile, BK=32, 256 threads, register-prefetch double buffering,
// transposed LDS so fragments are ds_read_b128.
// ---------------------------------------------------------------------------
template<int MODE>
__launch_bounds__(256)
__global__ void gemm_nt(const float* __restrict__ A,
                        const float* __restrict__ Bsrc0,
                        const float* __restrict__ Bsrc1,
                        const float* __restrict__ bias,
                        float* __restrict__ O0, float* __restrict__ O1, float* __restrict__ O2,
                        int M, int N, int K) {
    __shared__ float Asm[32][68];
    __shared__ float Bsm[32][68];
    const int tid = threadIdx.x;
    const int m0 = blockIdx.y * 64;
    const int n0 = blockIdx.x * 64;
    const int tx = tid & 15;
    const int ty = tid >> 4;
    const int r  = tid >> 5;
    const int c  = tid & 31;

    float regA[8], regB[8];
    const int NK = K >> 5;

    auto load_regs = [&](int kk) {
        #pragma unroll
        for (int i = 0; i < 8; ++i) {
            const int mr = r + i * 8;
            regA[i] = A[(size_t)(m0 + mr) * K + kk + c];
            const int nr = n0 + r + i * 8;
            const float* brow = (MODE == 1 && nr >= DI)
                              ? (Bsrc1 + (size_t)(nr - DI + DTR) * K)
                              : (Bsrc0 + (size_t)nr * K);
            regB[i] = brow[kk + c];
        }
    };

    float acc[4][4];
    #pragma unroll
    for (int i = 0; i < 4; ++i)
        #pragma unroll
        for (int j = 0; j < 4; ++j) acc[i][j] = 0.0f;

    load_regs(0);
    for (int it = 0; it < NK; ++it) {
        if (it > 0) __syncthreads();
        #pragma unroll
        for (int i = 0; i < 8; ++i) {
            Asm[c][r + i * 8] = regA[i];
            Bsm[c][r + i * 8] = regB[i];
        }
        __syncthreads();
        if (it + 1 < NK) load_regs((it + 1) << 5);
        #pragma unroll
        for (int k = 0; k < 32; ++k) {
            const float4 av = *(const float4*)&Asm[k][ty * 4];
            const float4 bv = *(const float4*)&Bsm[k][tx * 4];
            acc[0][0] = fmaf(av.x, bv.x, acc[0][0]);
            acc[0][1] = fmaf(av.x, bv.y, acc[0][1]);
            acc[0][2] = fmaf(av.x, bv.z, acc[0][2]);
            acc[0][3] = fmaf(av.x, bv.w, acc[0][3]);
            acc[1][0] = fmaf(av.y, bv.x, acc[1][0]);
            acc[1][1] = fmaf(av.y, bv.y, acc[1][1]);
            acc[1][2] = fmaf(av.y, bv.z, acc[1][2]);
            acc[1][3] = fmaf(av.y, bv.w, acc[1][3]);
            acc[2][0] = fmaf(av.z, bv.x, acc[2][0]);
            acc[2][1] = fmaf(av.z, bv.y, acc[2][1]);
            acc[2][2] = fmaf(av.z, bv.z, acc[2][2]);
            acc[2][3] = fmaf(av.z, bv.w, acc[2][3]);
            acc[3][0] = fmaf(av.w, bv.x, acc[3][0]);
            acc[3][1] = fmaf(av.w, bv.y, acc[3][1]);
            acc[3][2] = fmaf(av.w, bv.z, acc[3][2]);
            acc[3][3] = fmaf(av.w, bv.w, acc[3][3]);
        }
    }

    #pragma unroll
    for (int i = 0; i < 4; ++i) {
        const int gm = m0 + ty * 4 + i;
        #pragma unroll
        for (int j = 0; j < 4; ++j) {
            const int gn = n0 + tx * 4 + j;
            float v = acc[i][j] + (bias ? bias[gn] : 0.0f);
            if (MODE == 0) {
                if (gn < DI) O0[(size_t)gm * DI + gn] = v;
                else         O1[(size_t)gm * DI + (gn - DI)] = v * fast_sigmoid(v);
            } else if (MODE == 1) {
                if (gn < DI) {
                    float sp = (v > 20.0f) ? v : log1pf(__expf(v));
                    O0[(size_t)gm * DI + gn] = sp;               // delta
                } else if (gn < 2 * DI) {
                    O1[(size_t)gm * DS + (gn - DI)] = v;         // B
                } else {
                    O2[(size_t)gm * DS + (gn - 2 * DI)] = v;     // C
                }
            } else {
                O0[(size_t)gm * NE + gn] = v;
            }
        }
    }
}

// ---------------------------------------------------------------------------
__global__ void conv_silu_kernel(const float* __restrict__ xi,
                                 const float* __restrict__ conv_w,
                                 const float* __restrict__ conv_b,
                                 float* __restrict__ u) {
    const int idx = blockIdx.x * blockDim.x + threadIdx.x;
    if (idx >= SEQ * DI) return;
    const int l = idx / DI;
    const int d = idx - l * DI;
    const float4 w = ((const float4*)conv_w)[d];
    float acc = conv_b[d];
    if (l >= 3) acc = fmaf(xi[(size_t)(l - 3) * DI + d], w.x, acc);
    if (l >= 2) acc = fmaf(xi[(size_t)(l - 2) * DI + d], w.y, acc);
    if (l >= 1) acc = fmaf(xi[(size_t)(l - 1) * DI + d], w.z, acc);
    acc = fmaf(xi[(size_t)l * DI + d], w.w, acc);
    u[idx] = acc * fast_sigmoid(acc);
}

// ---------------------------------------------------------------------------
// Phase A: chunk-local scan. Block = (chunk k, channel d), 192 threads,
// each lane owns TWO states n = 2*tid, 2*tid+1 (float2 B/C loads).
// ---------------------------------------------------------------------------
__launch_bounds__(192)
__global__ void scanA_kernel(const float* __restrict__ delta,
                             const float* __restrict__ u,
                             const float* __restrict__ Bmat,
                             const float* __restrict__ Cmat,
                             const float* __restrict__ A_log,
                             float* __restrict__ ylocal,
                             float* __restrict__ hend,
                             float* __restrict__ Schunk) {
    const int k    = blockIdx.x;
    const int d    = blockIdx.y;
    const int tid  = threadIdx.x;
    const int lane = tid & 63;
    const int w    = tid >> 6;      // 0..2
    const int n0   = tid * 2;
    const int l0   = k * LC;

    __shared__ float2 s_dtu[LC];
    __shared__ float  part[12][LC + 1];

    if (tid < LC)            s_dtu[tid].x      = delta[(size_t)(l0 + tid) * DI + d];
    else if (tid < 2 * LC)   s_dtu[tid - LC].y = u[(size_t)(l0 + tid - LC) * DI + d];
    __syncthreads();

    const float2 al = *(const float2*)&A_log[(size_t)d * DS + n0];
    const float a0 = -__expf(al.x) * LOG2E;
    const float a1 = -__expf(al.y) * LOG2E;
    float h0 = 0.0f, h1 = 0.0f, S = 0.0f;

    const float2* __restrict__ bp = (const float2*)(Bmat + (size_t)l0 * DS) + tid;
    const float2* __restrict__ cp = (const float2*)(Cmat + (size_t)l0 * DS) + tid;

    #pragma unroll 4
    for (int l = 0; l < LC; ++l) {
        const float2 dtu = s_dtu[l];
        const float2 b = bp[(size_t)l * (DS / 2)];
        const float2 c = cp[(size_t)l * (DS / 2)];
        S += dtu.x;
        const float du = dtu.x * dtu.y;
        h0 = fmaf(EXP2F(dtu.x * a0), h0, du * b.x);
        h1 = fmaf(EXP2F(dtu.x * a1), h1, du * b.y);
        float p = fmaf(h1, c.y, h0 * c.x);
        p = row_reduce16(p);
        if ((lane & 15) == 15) part[(w << 2) | (lane >> 4)][l] = p;
    }

    *(float2*)&hend[(size_t)(d * NC + k) * DS + n0] = make_float2(h0, h1);
    if (tid == 0) Schunk[d * NC + k] = S;
    __syncthreads();

    if (tid < LC) {
        float y = 0.0f;
        #pragma unroll
        for (int r = 0; r < 12; ++r) y += part[r][tid];
        ylocal[(size_t)d * SEQ + l0 + tid] = y;
    }
}

// ---------------------------------------------------------------------------
// Phase B: cross-chunk combine; hend[d,k,:] becomes h_start for chunk k.
// ---------------------------------------------------------------------------
__launch_bounds__(DI)
__global__ void scanB_kernel(const float* __restrict__ A_log,
                             const float* __restrict__ Schunk,
                             float* __restrict__ hend) {
    const int d = blockIdx.x;
    const int n = threadIdx.x;
    const float a = -__expf(A_log[(size_t)d * DS + n]) * LOG2E;
    float H = 0.0f;
    #pragma unroll
    for (int k = 0; k < NC; ++k) {
        const float prev = H;
        const float dtot = EXP2F(a * Schunk[d * NC + k]);
        const float he   = hend[(size_t)(d * NC + k) * DS + n];
        H = fmaf(dtot, H, he);
        hend[(size_t)(d * NC + k) * DS + n] = prev;
    }
}

// ---------------------------------------------------------------------------
// Phase C: correction + gating. 192 threads, 2 states/lane.
// ---------------------------------------------------------------------------
__launch_bounds__(192)
__global__ void scanC_kernel(const float* __restrict__ delta,
                             const float* __restrict__ u,
                             const float* __restrict__ Cmat,
                             const float* __restrict__ A_log,
                             const float* __restrict__ Dvec,
                             const float* __restrict__ sres,
                             const float* __restrict__ ylocal,
                             const float* __restrict__ hstart,
                             float* __restrict__ yfin) {
    const int k    = blockIdx.x;
    const int d    = blockIdx.y;
    const int tid  = threadIdx.x;
    const int lane = tid & 63;
    const int w    = tid >> 6;
    const int n0   = tid * 2;
    const int l0   = k * LC;

    __shared__ float s_dt[LC];
    __shared__ float part[12][LC + 1];

    if (k > 0) {
        if (tid < LC) s_dt[tid] = delta[(size_t)(l0 + tid) * DI + d];
        __syncthreads();

        const float2 al = *(const float2*)&A_log[(size_t)d * DS + n0];
        const float a0 = -__expf(al.x) * LOG2E;
        const float a1 = -__expf(al.y) * LOG2E;
        float2 q = *(const float2*)&hstart[(size_t)(d * NC + k) * DS + n0];
        const float2* __restrict__ cp = (const float2*)(Cmat + (size_t)l0 * DS) + tid;

        #pragma unroll 4
        for (int l = 0; l < LC; ++l) {
            const float dt = s_dt[l];
            q.x *= EXP2F(dt * a0);
            q.y *= EXP2F(dt * a1);
            const float2 c = cp[(size_t)l * (DS / 2)];
            float p = fmaf(q.y, c.y, q.x * c.x);
            p = row_reduce16(p);
            if ((lane & 15) == 15) part[(w << 2) | (lane >> 4)][l] = p;
        }
        __syncthreads();
    }

    if (tid < LC) {
        const int l = l0 + tid;
        float y = ylocal[(size_t)d * SEQ + l];
        if (k > 0) {
            #pragma unroll
            for (int r = 0; r < 12; ++r) y += part[r][tid];
        }
        const float uv = u[(size_t)l * DI + d];
        const float sr = sres[(size_t)l * DI + d];
        yfin[(size_t)l * DI + d] = (y + uv * Dvec[d]) * sr;
    }
}

// ---------------------------------------------------------------------------
extern "C" void kernel_launch(void* const* d_in, const int* in_sizes, int n_in,
                              void* d_out, int out_size, void* d_ws, size_t ws_size,
                              hipStream_t stream) {
    const float* x      = (const float*)d_in[0];
    const float* W_in   = (const float*)d_in[1];
    const float* b_in   = (const float*)d_in[2];
    const float* conv_w = (const float*)d_in[3];
    const float* conv_b = (const float*)d_in[4];
    const float* W_xp   = (const float*)d_in[5];
    const float* W_dt   = (const float*)d_in[6];
    const float* A_log  = (const float*)d_in[7];
    const float* Dvec   = (const float*)d_in[8];
    const float* W_out  = (const float*)d_in[9];
    const float* b_out  = (const float*)d_in[10];
    float* out = (float*)d_out;

    float* ws = (float*)d_ws;
    const size_t LD = (size_t)SEQ * DI;   // 196608
    float* xi     = ws;
    float* sres   = ws + LD;
    float* u      = ws + 2 * LD;
    float* Bm     = ws + 3 * LD;
    float* Cm     = ws + 4 * LD;
    float* delta  = ws + 5 * LD;
    float* yfin   = ws + 6 * LD;
    float* ylocal = ws + 7 * LD;                    // [DI][SEQ]
    float* hend   = ws + 8 * LD;                    // [DI][NC][DS]
    float* Schunk = hend + (size_t)DI * NC * DS;    // [DI][NC]
    float* Wd     = Schunk + (size_t)DI * NC;       // [DI][DI]

    prep_wd<<<DI, DI, 0, stream>>>(W_dt, W_xp, Wd);
    gemm_nt<0><<<dim3(12, 8), 256, 0, stream>>>(x, W_in, nullptr, b_in,
                                                xi, sres, nullptr, SEQ, 2 * DI, NE);
    conv_silu_kernel<<<(SEQ * DI + 255) / 256, 256, 0, stream>>>(xi, conv_w, conv_b, u);
    gemm_nt<1><<<dim3(18, 8), 256, 0, stream>>>(u, Wd, W_xp, nullptr,
                                                delta, Bm, Cm, SEQ, 3 * DI, DI);
    scanA_kernel<<<dim3(NC, DI), 192, 0, stream>>>(delta, u, Bm, Cm, A_log,
                                                   ylocal, hend, Schunk);
    scanB_kernel<<<DI, DI, 0, stream>>>(A_log, Schunk, hend);
    scanC_kernel<<<dim3(NC, DI), 192, 0, stream>>>(delta, u, Cm, A_log, Dvec, sres,
                                                   ylocal, hend, yfin);
    gemm_nt<2><<<dim3(3, 8), 256, 0, stream>>>(yfin, W_out, nullptr, b_out,
                                               out, nullptr, nullptr, SEQ, NE, DI);
}